// Round 1
// baseline (151.333 us; speedup 1.0000x reference)
//
#include <hip/hip_runtime.h>
#include <math.h>

// SphericalExpansion: E edges scatter rb[8] x Y[16] x pw[4] into C centers.
// out[c, lm*32 + p*8 + n]  (verified: concat over l is just lm-major).
// Strategy: CSR build (hist/scan/scatter) then wave-per-center, lane=(lm,p).

static constexpr float PIF = 3.14159265358979323846f;

__global__ __launch_bounds__(256) void k_zero(int* __restrict__ p, int n) {
    int i = blockIdx.x * 256 + threadIdx.x;
    if (i < n) p[i] = 0;
}

__global__ __launch_bounds__(256) void k_hist(const int* __restrict__ centers,
                                              int* __restrict__ counts, int E) {
    int i = blockIdx.x * 256 + threadIdx.x;
    if (i < E) atomicAdd(&counts[centers[i]], 1);
}

// Single-block exclusive scan over C counts -> offsets[C+1], cursor[C].
__global__ __launch_bounds__(256) void k_scan(const int* __restrict__ counts,
                                              int* __restrict__ offsets,
                                              int* __restrict__ cursor, int C) {
    __shared__ int sums[256];
    int t = threadIdx.x;
    int per = (C + 255) >> 8;       // 64 for C=16384
    int base = t * per;
    int s = 0;
    for (int i = 0; i < per; ++i) {
        int idx = base + i;
        if (idx < C) s += counts[idx];
    }
    sums[t] = s;
    __syncthreads();
    for (int off = 1; off < 256; off <<= 1) {
        int v = sums[t];
        int add = (t >= off) ? sums[t - off] : 0;
        __syncthreads();
        sums[t] = v + add;
        __syncthreads();
    }
    int run = (t == 0) ? 0 : sums[t - 1];
    for (int i = 0; i < per; ++i) {
        int idx = base + i;
        if (idx < C) {
            offsets[idx] = run;
            cursor[idx] = run;
            run += counts[idx];
        }
    }
    if (t == 255) offsets[C] = run;
}

__global__ __launch_bounds__(256) void k_scatter(const int* __restrict__ centers,
                                                 int* __restrict__ cursor,
                                                 int* __restrict__ csr, int E) {
    int i = blockIdx.x * 256 + threadIdx.x;
    if (i < E) {
        int c = centers[i];
        int pos = atomicAdd(&cursor[c], 1);
        csr[pos] = i;
    }
}

__global__ __launch_bounds__(256) void k_main(const float* __restrict__ vec,
                                              const float* __restrict__ W,
                                              const int* __restrict__ species,
                                              const int* __restrict__ offsets,
                                              const int* __restrict__ csr,
                                              float* __restrict__ out, int C) {
    int lane = threadIdx.x & 63;
    int c = (blockIdx.x << 2) | (threadIdx.x >> 6);   // wave id = center id
    if (c >= C) return;
    int lm = lane >> 2;       // 0..15 -> which spherical harmonic
    int p  = lane & 3;        // 0..3  -> which pseudo channel
    float4 wrow = reinterpret_cast<const float4*>(W)[p];  // W[p][0..3]

    float a0 = 0.f, a1 = 0.f, a2 = 0.f, a3 = 0.f;
    float a4 = 0.f, a5 = 0.f, a6 = 0.f, a7 = 0.f;

    int beg = offsets[c], end = offsets[c + 1];
    for (int i = beg; i < end; ++i) {
        int e = csr[i];
        float vx = vec[3 * e + 0];
        float vy = vec[3 * e + 1];
        float vz = vec[3 * e + 2];
        int sp = species[e];
        float r2 = vx * vx + vy * vy + vz * vz;
        float r = __builtin_amdgcn_sqrtf(r2);
        if (r >= 4.0f) continue;   // fcut == 0 exactly -> contribution is 0

        float rinv = __builtin_amdgcn_rcpf(fmaxf(r, 1e-9f));
        float x = vx * rinv, y = vy * rinv, z = vz * rinv;

        // radial basis: rb[n] = sin((n+1)*th)/((n+1)*th) * fcut,  th = pi*r/4
        float th = r * (PIF * 0.25f);
        float s1 = __sinf(th), c1 = __cosf(th);
        float fcut = 0.5f * (c1 + 1.0f);
        float tdiv = fcut * __builtin_amdgcn_rcpf(fmaxf(th, 1e-12f));
        float twoc = c1 + c1;
        float s2 = twoc * s1;            // Chebyshev recurrence for sin(n*th)
        float s3 = twoc * s2 - s1;
        float s4 = twoc * s3 - s2;
        float s5 = twoc * s4 - s3;
        float s6 = twoc * s5 - s4;
        float s7 = twoc * s6 - s5;
        float s8 = twoc * s7 - s6;
        float rb0 = s1 * tdiv;
        float rb1 = s2 * tdiv * 0.5f;
        float rb2 = s3 * tdiv * (1.0f / 3.0f);
        float rb3 = s4 * tdiv * 0.25f;
        float rb4 = s5 * tdiv * 0.2f;
        float rb5 = s6 * tdiv * (1.0f / 6.0f);
        float rb6 = s7 * tdiv * (1.0f / 7.0f);
        float rb7 = s8 * tdiv * 0.125f;

        // real spherical harmonics l=0..3 (16 values)
        float xy = x * y, yz = y * z, xz = x * z;
        float x2 = x * x, y2 = y * y, z2 = z * z;
        float e0  = 0.28209479177387814f;
        float e1  = 0.4886025119029199f * y;
        float e2  = 0.4886025119029199f * z;
        float e3  = 0.4886025119029199f * x;
        float e4  = 1.0925484305920792f * xy;
        float e5  = 1.0925484305920792f * yz;
        float e6  = 0.31539156525252005f * (3.0f * z2 - 1.0f);
        float e7  = 1.0925484305920792f * xz;
        float e8  = 0.5462742152960396f * (x2 - y2);
        float f5  = 5.0f * z2 - 1.0f;
        float e9  = 0.5900435899266435f * y * (3.0f * x2 - y2);
        float e10 = 2.890611442640554f * xy * z;
        float e11 = 0.4570457994644658f * y * f5;
        float e12 = 0.3731763325901154f * z * (5.0f * z2 - 3.0f);
        float e13 = 0.4570457994644658f * x * f5;
        float e14 = 1.445305721320277f * z * (x2 - y2);
        float e15 = 0.5900435899266435f * x * (x2 - 3.0f * y2);

        // select Y[lm] via cndmask tree (lm is per-lane constant)
        bool b3 = (lm & 8) != 0, b2 = (lm & 4) != 0;
        bool b1 = (lm & 2) != 0, b0 = (lm & 1) != 0;
        float t0 = b3 ? e8  : e0;
        float t1 = b3 ? e9  : e1;
        float t2 = b3 ? e10 : e2;
        float t3 = b3 ? e11 : e3;
        float t4 = b3 ? e12 : e4;
        float t5 = b3 ? e13 : e5;
        float t6 = b3 ? e14 : e6;
        float t7 = b3 ? e15 : e7;
        float u0 = b2 ? t4 : t0;
        float u1 = b2 ? t5 : t1;
        float u2 = b2 ? t6 : t2;
        float u3 = b2 ? t7 : t3;
        float v0 = b1 ? u2 : u0;
        float v1 = b1 ? u3 : u1;
        float ysel = b0 ? v1 : v0;

        // pw = W[p, species]
        float pw = (sp == 0) ? wrow.x : (sp == 1) ? wrow.y : (sp == 2) ? wrow.z : wrow.w;
        float coef = ysel * pw;

        a0 = fmaf(coef, rb0, a0);
        a1 = fmaf(coef, rb1, a1);
        a2 = fmaf(coef, rb2, a2);
        a3 = fmaf(coef, rb3, a3);
        a4 = fmaf(coef, rb4, a4);
        a5 = fmaf(coef, rb5, a5);
        a6 = fmaf(coef, rb6, a6);
        a7 = fmaf(coef, rb7, a7);
    }

    // lane (lm,p) owns out[c, lane*8 .. lane*8+7]; wave writes 512 contiguous floats
    float4 o0 = make_float4(a0, a1, a2, a3);
    float4 o1 = make_float4(a4, a5, a6, a7);
    float4* op = reinterpret_cast<float4*>(out + (size_t)c * 512 + lane * 8);
    op[0] = o0;
    op[1] = o1;
}

extern "C" void kernel_launch(void* const* d_in, const int* in_sizes, int n_in,
                              void* d_out, int out_size, void* d_ws, size_t ws_size,
                              hipStream_t stream) {
    const float* vec     = (const float*)d_in[0];
    const float* W       = (const float*)d_in[1];
    const int*   centers = (const int*)d_in[2];
    const int*   species = (const int*)d_in[3];
    int E = in_sizes[2];
    int C = out_size / 512;
    float* out = (float*)d_out;

    int* ws = (int*)d_ws;
    int* counts  = ws;               // C ints
    int* offsets = ws + C;           // C+1 ints
    int* cursor  = ws + 2 * C + 1;   // C ints
    int* csr     = ws + 3 * C + 1;   // E ints

    hipLaunchKernelGGL(k_zero,    dim3((C + 255) / 256), dim3(256), 0, stream, counts, C);
    hipLaunchKernelGGL(k_hist,    dim3((E + 255) / 256), dim3(256), 0, stream, centers, counts, E);
    hipLaunchKernelGGL(k_scan,    dim3(1),               dim3(256), 0, stream, counts, offsets, cursor, C);
    hipLaunchKernelGGL(k_scatter, dim3((E + 255) / 256), dim3(256), 0, stream, centers, cursor, csr, E);
    hipLaunchKernelGGL(k_main,    dim3((C + 3) / 4),     dim3(256), 0, stream, vec, W, species, offsets, csr, out, C);
}

// Round 2
// 117.782 us; speedup vs baseline: 1.2848x; 1.2848x over previous
//
#include <hip/hip_runtime.h>
#include <math.h>

// SphericalExpansion: E edges scatter rb[8] x Y[16] x pw[4] into C centers.
// out[c, lm*32 + p*8 + n].
// R2: geometry moved to lane-parallel precompute+scatter pass writing sorted
// 28-float records {rb[8], Y[16], pw[4]}; accumulate is 12 instrs/edge.

static constexpr float PIF = 3.14159265358979323846f;
static constexpr int REC = 28;   // floats per edge record (112 B, 16B-aligned)

__global__ __launch_bounds__(256) void k_hist(const int* __restrict__ centers,
                                              int* __restrict__ counts, int E) {
    int i = blockIdx.x * 256 + threadIdx.x;
    if (i < E) atomicAdd(&counts[centers[i]], 1);
}

// Single-block exclusive scan over C counts -> offsets[C+1], cursor[C].
__global__ __launch_bounds__(256) void k_scan(const int* __restrict__ counts,
                                              int* __restrict__ offsets,
                                              int* __restrict__ cursor, int C) {
    __shared__ int sums[256];
    int t = threadIdx.x;
    int per = (C + 255) >> 8;
    int base = t * per;
    int s = 0;
    for (int i = 0; i < per; ++i) {
        int idx = base + i;
        if (idx < C) s += counts[idx];
    }
    sums[t] = s;
    __syncthreads();
    for (int off = 1; off < 256; off <<= 1) {
        int v = sums[t];
        int add = (t >= off) ? sums[t - off] : 0;
        __syncthreads();
        sums[t] = v + add;
        __syncthreads();
    }
    int run = (t == 0) ? 0 : sums[t - 1];
    for (int i = 0; i < per; ++i) {
        int idx = base + i;
        if (idx < C) {
            offsets[idx] = run;
            cursor[idx] = run;
            run += counts[idx];
        }
    }
    if (t == 255) offsets[C] = run;
}

// One thread per edge: claim CSR slot, compute geometry, write sorted record.
__global__ __launch_bounds__(256) void k_pre(const float* __restrict__ vec,
                                             const float* __restrict__ W,
                                             const int* __restrict__ species,
                                             const int* __restrict__ centers,
                                             int* __restrict__ cursor,
                                             float* __restrict__ rec, int E) {
    int i = blockIdx.x * 256 + threadIdx.x;
    if (i >= E) return;
    int c = centers[i];
    int pos = atomicAdd(&cursor[c], 1);

    float vx = vec[3 * i + 0];
    float vy = vec[3 * i + 1];
    float vz = vec[3 * i + 2];
    int sp = species[i];

    float r2 = fmaf(vx, vx, fmaf(vy, vy, vz * vz));
    float r = sqrtf(r2);
    float rinv = __builtin_amdgcn_rcpf(fmaxf(r, 1e-9f));
    float x = vx * rinv, y = vy * rinv, z = vz * rinv;

    // rb[n] = sin((n+1)*th)/((n+1)*th) * fcut, th = pi*r/4; fcut=0 for r>=4
    float th = r * (PIF * 0.25f);
    float s1 = __sinf(th), c1 = __cosf(th);
    float fcut = (r < 4.0f) ? 0.5f * (c1 + 1.0f) : 0.0f;
    float tdiv = fcut * __builtin_amdgcn_rcpf(fmaxf(th, 1e-12f));
    float twoc = c1 + c1;
    float s2 = twoc * s1;
    float s3 = twoc * s2 - s1;
    float s4 = twoc * s3 - s2;
    float s5 = twoc * s4 - s3;
    float s6 = twoc * s5 - s4;
    float s7 = twoc * s6 - s5;
    float s8 = twoc * s7 - s6;

    float xy = x * y, yz = y * z, xz = x * z;
    float x2 = x * x, y2 = y * y, z2 = z * z;
    float f5 = 5.0f * z2 - 1.0f;

    float* rp = rec + (size_t)pos * REC;
    float4 o;
    o.x = s1 * tdiv;
    o.y = s2 * tdiv * 0.5f;
    o.z = s3 * tdiv * (1.0f / 3.0f);
    o.w = s4 * tdiv * 0.25f;
    reinterpret_cast<float4*>(rp)[0] = o;
    o.x = s5 * tdiv * 0.2f;
    o.y = s6 * tdiv * (1.0f / 6.0f);
    o.z = s7 * tdiv * (1.0f / 7.0f);
    o.w = s8 * tdiv * 0.125f;
    reinterpret_cast<float4*>(rp)[1] = o;
    o.x = 0.28209479177387814f;
    o.y = 0.4886025119029199f * y;
    o.z = 0.4886025119029199f * z;
    o.w = 0.4886025119029199f * x;
    reinterpret_cast<float4*>(rp)[2] = o;
    o.x = 1.0925484305920792f * xy;
    o.y = 1.0925484305920792f * yz;
    o.z = 0.31539156525252005f * (3.0f * z2 - 1.0f);
    o.w = 1.0925484305920792f * xz;
    reinterpret_cast<float4*>(rp)[3] = o;
    o.x = 0.5462742152960396f * (x2 - y2);
    o.y = 0.5900435899266435f * y * (3.0f * x2 - y2);
    o.z = 2.890611442640554f * xy * z;
    o.w = 0.4570457994644658f * y * f5;
    reinterpret_cast<float4*>(rp)[4] = o;
    o.x = 0.3731763325901154f * z * (5.0f * z2 - 3.0f);
    o.y = 0.4570457994644658f * x * f5;
    o.z = 1.445305721320277f * z * (x2 - y2);
    o.w = 0.5900435899266435f * x * (x2 - 3.0f * y2);
    reinterpret_cast<float4*>(rp)[5] = o;
    o.x = W[0 * 4 + sp];
    o.y = W[1 * 4 + sp];
    o.z = W[2 * 4 + sp];
    o.w = W[3 * 4 + sp];
    reinterpret_cast<float4*>(rp)[6] = o;
}

// Wave per center; lane (lm,p); 12 instrs/edge, unrolled x2.
__global__ __launch_bounds__(256) void k_accum(const int* __restrict__ offsets,
                                               const float* __restrict__ rec,
                                               float* __restrict__ out, int C) {
    int lane = threadIdx.x & 63;
    int c = (blockIdx.x << 2) | (threadIdx.x >> 6);
    if (c >= C) return;
    int lm = lane >> 2;
    int p = lane & 3;

    float a0 = 0.f, a1 = 0.f, a2 = 0.f, a3 = 0.f;
    float a4 = 0.f, a5 = 0.f, a6 = 0.f, a7 = 0.f;

    int beg = offsets[c], end = offsets[c + 1];
    int i = beg;
    for (; i + 1 < end; i += 2) {
        const float* r0 = rec + (size_t)i * REC;
        const float* r1 = r0 + REC;
        float4 b00 = *reinterpret_cast<const float4*>(r0);
        float4 b01 = *reinterpret_cast<const float4*>(r0 + 4);
        float y0 = r0[8 + lm];
        float w0 = r0[24 + p];
        float4 b10 = *reinterpret_cast<const float4*>(r1);
        float4 b11 = *reinterpret_cast<const float4*>(r1 + 4);
        float y1 = r1[8 + lm];
        float w1 = r1[24 + p];
        float c0 = y0 * w0;
        float c1 = y1 * w1;
        a0 = fmaf(c0, b00.x, a0);
        a1 = fmaf(c0, b00.y, a1);
        a2 = fmaf(c0, b00.z, a2);
        a3 = fmaf(c0, b00.w, a3);
        a4 = fmaf(c0, b01.x, a4);
        a5 = fmaf(c0, b01.y, a5);
        a6 = fmaf(c0, b01.z, a6);
        a7 = fmaf(c0, b01.w, a7);
        a0 = fmaf(c1, b10.x, a0);
        a1 = fmaf(c1, b10.y, a1);
        a2 = fmaf(c1, b10.z, a2);
        a3 = fmaf(c1, b10.w, a3);
        a4 = fmaf(c1, b11.x, a4);
        a5 = fmaf(c1, b11.y, a5);
        a6 = fmaf(c1, b11.z, a6);
        a7 = fmaf(c1, b11.w, a7);
    }
    if (i < end) {
        const float* r0 = rec + (size_t)i * REC;
        float4 b00 = *reinterpret_cast<const float4*>(r0);
        float4 b01 = *reinterpret_cast<const float4*>(r0 + 4);
        float c0 = r0[8 + lm] * r0[24 + p];
        a0 = fmaf(c0, b00.x, a0);
        a1 = fmaf(c0, b00.y, a1);
        a2 = fmaf(c0, b00.z, a2);
        a3 = fmaf(c0, b00.w, a3);
        a4 = fmaf(c0, b01.x, a4);
        a5 = fmaf(c0, b01.y, a5);
        a6 = fmaf(c0, b01.z, a6);
        a7 = fmaf(c0, b01.w, a7);
    }

    float4* op = reinterpret_cast<float4*>(out + (size_t)c * 512 + lane * 8);
    op[0] = make_float4(a0, a1, a2, a3);
    op[1] = make_float4(a4, a5, a6, a7);
}

extern "C" void kernel_launch(void* const* d_in, const int* in_sizes, int n_in,
                              void* d_out, int out_size, void* d_ws, size_t ws_size,
                              hipStream_t stream) {
    const float* vec     = (const float*)d_in[0];
    const float* W       = (const float*)d_in[1];
    const int*   centers = (const int*)d_in[2];
    const int*   species = (const int*)d_in[3];
    int E = in_sizes[2];
    int C = out_size / 512;
    float* out = (float*)d_out;

    int* ws = (int*)d_ws;
    int*   counts  = ws;                       // C ints
    int*   offsets = ws + C;                   // C+1 ints
    int*   cursor  = ws + 2 * C + 1;           // C ints
    float* rec     = (float*)(ws + 3 * C + 4); // E*REC floats, 16B-aligned

    hipMemsetAsync(counts, 0, (size_t)C * sizeof(int), stream);
    hipLaunchKernelGGL(k_hist,  dim3((E + 255) / 256), dim3(256), 0, stream, centers, counts, E);
    hipLaunchKernelGGL(k_scan,  dim3(1),               dim3(256), 0, stream, counts, offsets, cursor, C);
    hipLaunchKernelGGL(k_pre,   dim3((E + 255) / 256), dim3(256), 0, stream, vec, W, species, centers, cursor, rec, E);
    hipLaunchKernelGGL(k_accum, dim3((C + 3) / 4),     dim3(256), 0, stream, offsets, rec, out, C);
}